// Round 1
// baseline (1355.325 us; speedup 1.0000x reference)
//
#include <hip/hip_runtime.h>
#include <hip/hip_bf16.h>
#include <cstddef>

// Problem constants (match reference)
#define NN   20000     // NU == NI
#define EE   200000
#define HH   8
#define DD   64
#define FF   512
#define BB   1024
#define PP   8
#define KK   8

// ---------------------------------------------------------------------------
// fc: f = h @ W  (N x 64) * (64 x 512), fused el/er epilogue.
// Block: 512 threads = 8 waves; wave w owns head w (cols 64w..64w+63).
// Each block computes 8 rows (N = 20000 = 2500 * 8 exactly).
// ---------------------------------------------------------------------------
__global__ __launch_bounds__(512) void fc_kernel(
    const float* __restrict__ h,    // [N,64]
    const float* __restrict__ W,    // [64,512]
    const float* __restrict__ al,   // [8,64]
    const float* __restrict__ ar,   // [8,64]
    float* __restrict__ f,          // [N,512]
    float* __restrict__ el,         // [N,8]
    float* __restrict__ er)         // [N,8]
{
    const int j  = threadIdx.x;          // column 0..511
    const int r0 = blockIdx.x * 8;
    __shared__ float hl[8][64];
    {
        int tr = j >> 6, td = j & 63;
        hl[tr][td] = h[(r0 + tr) * 64 + td];
    }
    __syncthreads();

    float acc[8];
#pragma unroll
    for (int r = 0; r < 8; ++r) acc[r] = 0.f;

    for (int d = 0; d < 64; ++d) {
        float w = W[d * 512 + j];
#pragma unroll
        for (int r = 0; r < 8; ++r) acc[r] += hl[r][d] * w;
    }

#pragma unroll
    for (int r = 0; r < 8; ++r) f[(r0 + r) * 512 + j] = acc[r];

    // el/er epilogue: head = j>>6, in-head lane = j&63 (== wave lane)
    const float a_l = al[j];   // al[h*64 + d] with h=j>>6, d=j&63 -> al[j]
    const float a_r = ar[j];
#pragma unroll
    for (int r = 0; r < 8; ++r) {
        float vl = acc[r] * a_l;
        float vr = acc[r] * a_r;
#pragma unroll
        for (int off = 32; off; off >>= 1) {
            vl += __shfl_down(vl, off, 64);
            vr += __shfl_down(vr, off, 64);
        }
        if ((j & 63) == 0) {
            el[(r0 + r) * 8 + (j >> 6)] = vl;
            er[(r0 + r) * 8 + (j >> 6)] = vr;
        }
    }
}

// ---------------------------------------------------------------------------
// CSR build: zero -> histogram -> scan -> scatter
// ---------------------------------------------------------------------------
__global__ void zero_kernel(int* __restrict__ count, int* __restrict__ cursor,
                            float* __restrict__ wsum, int n, int zero_wsum)
{
    int i = blockIdx.x * blockDim.x + threadIdx.x;
    if (i < n) { count[i] = 0; cursor[i] = 0; }
    if (zero_wsum && i < 2) wsum[i] = 0.f;
}

__global__ void hist_kernel(const int* __restrict__ dst, int* __restrict__ count, int e)
{
    int i = blockIdx.x * blockDim.x + threadIdx.x;
    if (i < e) atomicAdd(&count[dst[i]], 1);
}

__global__ __launch_bounds__(256) void scan_kernel(
    const int* __restrict__ count, int* __restrict__ row_off, int n)
{
    __shared__ int part[256];
    __shared__ int base[257];
    const int tid = threadIdx.x;
    const int chunk = (n + 255) / 256;
    const int start = tid * chunk;
    const int end   = min(start + chunk, n);
    int s = 0;
    for (int i = start; i < end; ++i) s += count[i];
    part[tid] = s;
    __syncthreads();
    if (tid == 0) {
        int acc = 0;
        for (int i = 0; i < 256; ++i) { base[i] = acc; acc += part[i]; }
        base[256] = acc;
    }
    __syncthreads();
    int acc = base[tid];
    for (int i = start; i < end; ++i) { row_off[i] = acc; acc += count[i]; }
    if (tid == 0) row_off[n] = base[256];
}

__global__ void scatter_kernel(const int* __restrict__ src, const int* __restrict__ dst,
                               const int* __restrict__ row_off, int* __restrict__ cursor,
                               int* __restrict__ csr_src, int e)
{
    int i = blockIdx.x * blockDim.x + threadIdx.x;
    if (i < e) {
        int d = dst[i];
        int p = atomicAdd(&cursor[d], 1);
        csr_src[row_off[d] + p] = src[i];
    }
}

// ---------------------------------------------------------------------------
// Aggregation: one block (128 threads) per dst node.
// out[n] = elu( (sum_e exp(leaky(el[src]+er[n])) * f[src]) / max(sum_e ex,1e-9) + b )
// No max subtraction (values are tiny; alpha is mathematically identical).
// Thread t handles float4 at column 4t; its head h = t>>4 (16 threads/head,
// redundant scalar work per head avoids any intra-block sync in the loop).
// ---------------------------------------------------------------------------
__global__ __launch_bounds__(128) void agg_kernel(
    const float* __restrict__ f,      // [N,512]
    const float* __restrict__ el,     // [N,8]
    const float* __restrict__ er,     // [N,8]
    const int* __restrict__ row_off,  // [N+1]
    const int* __restrict__ csr_src,  // [E]
    const float* __restrict__ bias,   // [512]
    float* __restrict__ z)            // [N,512]
{
    const int n   = blockIdx.x;
    const int tid = threadIdx.x;            // 0..127
    const int h   = tid >> 4;               // head for this thread's columns
    const float ern = er[n * 8 + h];
    const int beg = row_off[n], end = row_off[n + 1];

    float s = 0.f;
    float4 acc = make_float4(0.f, 0.f, 0.f, 0.f);
    for (int e = beg; e < end; ++e) {
        int src = csr_src[e];
        float x = el[src * 8 + h] + ern;
        x = (x >= 0.f) ? x : 0.2f * x;
        float ex = expf(x);
        s += ex;
        const float4 fv = *(const float4*)(f + src * 512 + tid * 4);
        acc.x += ex * fv.x; acc.y += ex * fv.y;
        acc.z += ex * fv.z; acc.w += ex * fv.w;
    }
    const float inv = 1.f / fmaxf(s, 1e-9f);
    const float4 b4 = *(const float4*)(bias + tid * 4);
    float4 o;
    float v;
    v = acc.x * inv + b4.x; o.x = (v > 0.f) ? v : expm1f(v);
    v = acc.y * inv + b4.y; o.y = (v > 0.f) ? v : expm1f(v);
    v = acc.z * inv + b4.z; o.z = (v > 0.f) ? v : expm1f(v);
    v = acc.w * inv + b4.w; o.w = (v > 0.f) ? v : expm1f(v);
    *(float4*)(z + n * 512 + tid * 4) = o;
}

// ---------------------------------------------------------------------------
// Semantic attention GEMM: rows = [2N] of z ([2][N][512]), cols = 128.
// q = tanh(z @ W1 + b1) @ v ; accumulate sum_n q into wsum[m].
// Block: 256 threads = 2 rowgroups x 128 cols; 16 rows/block (2N = 2500*16).
// Plane boundary falls exactly on a block boundary (block 1250).
// ---------------------------------------------------------------------------
__global__ __launch_bounds__(256) void sem_kernel(
    const float* __restrict__ z,    // [2N,512]
    const float* __restrict__ W1,   // [512,128]
    const float* __restrict__ b1,   // [128]
    const float* __restrict__ vv,   // [128]
    float* __restrict__ wsum)       // [2]
{
    __shared__ float zl[16][512];   // 32 KB
    __shared__ float red[4][8];
    const int tid = threadIdx.x;
    const int r0  = blockIdx.x * 16;

    for (int i = tid; i < 16 * 128; i += 256) {     // 2048 float4
        int rr = i >> 7, cc = i & 127;
        *(float4*)&zl[rr][cc * 4] = *(const float4*)&z[(r0 + rr) * 512 + cc * 4];
    }
    __syncthreads();

    const int j  = tid & 127;
    const int rg = tid >> 7;
    float acc[8];
#pragma unroll
    for (int r = 0; r < 8; ++r) acc[r] = 0.f;

    for (int d = 0; d < 512; ++d) {
        float w = W1[d * 128 + j];
#pragma unroll
        for (int r = 0; r < 8; ++r) acc[r] += zl[rg * 8 + r][d] * w;
    }

    const float bj = b1[j], vj = vv[j];
#pragma unroll
    for (int r = 0; r < 8; ++r) {
        float q = tanhf(acc[r] + bj) * vj;
#pragma unroll
        for (int off = 32; off; off >>= 1) q += __shfl_down(q, off, 64);
        if ((tid & 63) == 0) red[tid >> 6][r] = q;
    }
    __syncthreads();
    if (tid == 0) {
        float tot = 0.f;
#pragma unroll
        for (int r = 0; r < 8; ++r)
            tot += red[0][r] + red[1][r] + red[2][r] + red[3][r];
        atomicAdd(wsum + (blockIdx.x >= 1250 ? 1 : 0), tot);
    }
}

// ---------------------------------------------------------------------------
// Combine: beta = softmax(wsum / N); h_out = beta0*z[0] + beta1*z[1]
// ---------------------------------------------------------------------------
__global__ void combine_kernel(const float* __restrict__ z,
                               const float* __restrict__ wsum,
                               float* __restrict__ hout)
{
    const float w0 = wsum[0] * (1.f / (float)NN);
    const float w1 = wsum[1] * (1.f / (float)NN);
    const float m  = fmaxf(w0, w1);
    const float e0 = expf(w0 - m), e1 = expf(w1 - m);
    const float is = 1.f / (e0 + e1);
    const float b0 = e0 * is, b1 = e1 * is;
    int i = blockIdx.x * blockDim.x + threadIdx.x;   // float4 index
    if (i < NN * 128) {
        float4 z0 = ((const float4*)z)[i];
        float4 z1 = ((const float4*)z)[i + NN * 128];
        float4 o;
        o.x = b0 * z0.x + b1 * z1.x;
        o.y = b0 * z0.y + b1 * z1.y;
        o.z = b0 * z0.z + b1 * z1.z;
        o.w = b0 * z0.w + b1 * z1.w;
        ((float4*)hout)[i] = o;
    }
}

// ---------------------------------------------------------------------------
// Scoring + output assembly. Block per (b,p) = 8192 blocks, 128 threads.
// out layout (floats): pos_logits[8192] | neg_logits[65536] |
//   ue_n[33554432] | pe[4194304] | ne[33554432]
// ---------------------------------------------------------------------------
__global__ __launch_bounds__(128) void score_kernel(
    const float* __restrict__ hu, const float* __restrict__ hi,
    const int* __restrict__ uid, const int* __restrict__ pos,
    const int* __restrict__ neg, float* __restrict__ out)
{
    const int bp  = blockIdx.x;          // b*P + p
    const int b   = bp >> 3;
    const int tid = threadIdx.x;         // float4 column
    __shared__ float red[2];

    float* pos_logits = out;
    float* neg_logits = out + 8192;
    float* ue_n       = out + 73728;
    float* pe         = out + 33628160;
    float* ne         = out + 37822464;

    const float4 u4 = ((const float4*)(hu + (size_t)uid[b] * 512))[tid];

    // positive
    {
        const float4 p4 = ((const float4*)(hi + (size_t)pos[bp] * 512))[tid];
        ((float4*)(pe + (size_t)bp * 512))[tid] = p4;
        float d = u4.x * p4.x + u4.y * p4.y + u4.z * p4.z + u4.w * p4.w;
#pragma unroll
        for (int off = 32; off; off >>= 1) d += __shfl_down(d, off, 64);
        if ((tid & 63) == 0) red[tid >> 6] = d;
        __syncthreads();
        if (tid == 0) pos_logits[bp] = red[0] + red[1];
    }
    // negatives
    for (int k = 0; k < KK; ++k) {
        __syncthreads();
        const size_t row = (size_t)bp * KK + k;
        const float4 n4 = ((const float4*)(hi + (size_t)neg[row] * 512))[tid];
        ((float4*)(ne   + row * 512))[tid] = n4;
        ((float4*)(ue_n + row * 512))[tid] = u4;
        float d = u4.x * n4.x + u4.y * n4.y + u4.z * n4.z + u4.w * n4.w;
#pragma unroll
        for (int off = 32; off; off >>= 1) d += __shfl_down(d, off, 64);
        if ((tid & 63) == 0) red[tid >> 6] = d;
        __syncthreads();
        if (tid == 0) neg_logits[row] = red[0] + red[1];
    }
}

// ---------------------------------------------------------------------------
extern "C" void kernel_launch(void* const* d_in, const int* in_sizes, int n_in,
                              void* d_out, int out_size, void* d_ws, size_t ws_size,
                              hipStream_t stream)
{
    const float* user_embs = (const float*)d_in[0];
    const float* item_embs = (const float*)d_in[1];
    const float* Wg_u = (const float*)d_in[2];
    const float* al_u = (const float*)d_in[3];
    const float* ar_u = (const float*)d_in[4];
    const float* bg_u = (const float*)d_in[5];
    const float* Ws_u = (const float*)d_in[6];
    const float* bs_u = (const float*)d_in[7];
    const float* vs_u = (const float*)d_in[8];
    const float* Wg_i = (const float*)d_in[9];
    const float* al_i = (const float*)d_in[10];
    const float* ar_i = (const float*)d_in[11];
    const float* bg_i = (const float*)d_in[12];
    const float* Ws_i = (const float*)d_in[13];
    const float* bs_i = (const float*)d_in[14];
    const float* vs_i = (const float*)d_in[15];
    const int* src_u = (const int*)d_in[16];
    const int* dst_u = (const int*)d_in[17];
    const int* src_i = (const int*)d_in[18];
    const int* dst_i = (const int*)d_in[19];
    const int* uid = (const int*)d_in[20];
    const int* pos = (const int*)d_in[21];
    const int* neg = (const int*)d_in[22];

    // workspace carve-up (~198 MiB)
    float* f    = (float*)d_ws;               // [N,512]
    float* z    = f  + (size_t)NN * 512;      // [2,N,512]
    float* hu   = z  + (size_t)2 * NN * 512;  // [N,512]
    float* hi   = hu + (size_t)NN * 512;      // [N,512]
    float* el   = hi + (size_t)NN * 512;      // [N,8]
    float* er   = el + (size_t)NN * 8;        // [N,8]
    float* wsum = er + (size_t)NN * 8;        // [2] (+pad)
    int* count  = (int*)(wsum + 8);           // [N]
    int* roff   = count + NN;                 // [N+1]
    int* cursor = roff + NN + 8;              // [N]
    int* csrc   = cursor + NN;                // [E]

    for (int t = 0; t < 2; ++t) {
        const float* h0 = t ? item_embs : user_embs;
        const float* Wg = t ? Wg_i : Wg_u;
        const float* al = t ? al_i : al_u;
        const float* ar = t ? ar_i : ar_u;
        const float* bg = t ? bg_i : bg_u;
        const float* W1 = t ? Ws_i : Ws_u;
        const float* b1 = t ? bs_i : bs_u;
        const float* vv = t ? vs_i : vs_u;
        const int* srcA = t ? src_i : src_u;
        const int* dstA = t ? dst_i : dst_u;
        float* hout = t ? hi : hu;

        for (int g = 0; g < 2; ++g) {
            fc_kernel<<<NN / 8, 512, 0, stream>>>(
                h0, Wg + (size_t)g * 64 * 512, al + g * 512, ar + g * 512,
                f, el, er);
            zero_kernel<<<(NN + 255) / 256, 256, 0, stream>>>(
                count, cursor, wsum, NN, g == 0 ? 1 : 0);
            hist_kernel<<<(EE + 255) / 256, 256, 0, stream>>>(
                dstA + (size_t)g * EE, count, EE);
            scan_kernel<<<1, 256, 0, stream>>>(count, roff, NN);
            scatter_kernel<<<(EE + 255) / 256, 256, 0, stream>>>(
                srcA + (size_t)g * EE, dstA + (size_t)g * EE, roff, cursor, csrc, EE);
            agg_kernel<<<NN, 128, 0, stream>>>(
                f, el, er, roff, csrc, bg + g * 512, z + (size_t)g * NN * 512);
        }
        sem_kernel<<<2 * NN / 16, 256, 0, stream>>>(z, W1, b1, vv, wsum);
        combine_kernel<<<(NN * 128 + 255) / 256, 256, 0, stream>>>(z, wsum, hout);
    }

    score_kernel<<<BB * PP, 128, 0, stream>>>(hu, hi, uid, pos, neg, (float*)d_out);
}

// Round 6
// 717.250 us; speedup vs baseline: 1.8896x; 1.8896x over previous
//
#include <hip/hip_runtime.h>
#include <hip/hip_bf16.h>
#include <cstddef>

#define NN 20000
#define EE 200000

typedef __attribute__((ext_vector_type(8))) short bf8_t;   // 8 bf16 (4 VGPRs)
typedef __attribute__((ext_vector_type(4))) float f32x4;   // MFMA acc

__device__ __forceinline__ float bf2f(unsigned int lo16) {
    return __uint_as_float(lo16 << 16);
}
__device__ __forceinline__ unsigned short f2bf(float f) {   // RNE
    unsigned u = __float_as_uint(f);
    u += 0x7fffu + ((u >> 16) & 1u);
    return (unsigned short)(u >> 16);
}

// ---------------------------------------------------------------------------
// prep: pack h -> bf16, W -> bf16 transposed [col][k], W1 -> bf16 [col][k]
// ---------------------------------------------------------------------------
__global__ void prep_kernel(
    const float* __restrict__ user_embs, const float* __restrict__ item_embs,
    const float* __restrict__ Wg_u, const float* __restrict__ Wg_i,
    const float* __restrict__ Ws_u, const float* __restrict__ Ws_i,
    unsigned short* __restrict__ hb,     // [2][NN*64]
    unsigned short* __restrict__ Wt,     // [4][512*64]  (col*64 + k)
    unsigned short* __restrict__ W1t)    // [2][128*512] (c*512 + k)
{
    int i = blockIdx.x * 256 + threadIdx.x;
    if (i < 2 * NN * 64) {
        float v = (i < NN * 64) ? user_embs[i] : item_embs[i - NN * 64];
        hb[i] = f2bf(v);
    }
    if (i < 4 * 512 * 64) {
        int tg = i >> 15, rem = i & 32767;
        int col = rem >> 6, k = rem & 63;
        const float* W = (tg < 2 ? Wg_u + tg * 32768 : Wg_i + (tg - 2) * 32768);
        Wt[i] = f2bf(W[k * 512 + col]);
    }
    if (i < 2 * 128 * 512) {
        int t = i >> 16, rem = i & 65535;
        int c = rem >> 9, k = rem & 511;
        const float* Wsrc = t ? Ws_i : Ws_u;
        W1t[i] = f2bf(Wsrc[k * 128 + c]);
    }
}

// ---------------------------------------------------------------------------
// fc (MFMA): f[tg] = h[t] @ W[tg], fused el/er epilogue from fp32 acc.
// Block 256 = 4 waves; tile 16 rows x 512 cols; wave w: cols w*128..+128
// (= heads 2w,2w+1 exactly -> el/er wave-local, no cross-wave reduce).
// Fragment maps (m89/m91-verified): A row=l&15, k=(l>>4)*8+j;
// B(col-major-K) col=l&15; D col=l&15, row=(l>>4)*4+r.
// ---------------------------------------------------------------------------
__global__ __launch_bounds__(256) void fc_kernel(
    const unsigned short* __restrict__ hb,
    const unsigned short* __restrict__ Wt,
    const float* __restrict__ al_u, const float* __restrict__ ar_u,
    const float* __restrict__ al_i, const float* __restrict__ ar_i,
    unsigned short* __restrict__ fb,     // [4][NN*512] bf16
    float* __restrict__ el, float* __restrict__ er)  // [4][NN*8]
{
    const int tg = blockIdx.y, t = tg >> 1, g = tg & 1;
    const int tid = threadIdx.x, wid = tid >> 6, lane = tid & 63;
    const int r0 = blockIdx.x * 16;
    const unsigned short* A = hb + (size_t)t * NN * 64;
    const unsigned short* B = Wt + (size_t)tg * 512 * 64;
    const float* alf = (t ? al_i : al_u) + g * 512;
    const float* arf = (t ? ar_i : ar_u) + g * 512;

    const int arow = lane & 15, ak0 = (lane >> 4) * 8;
    const bf8_t a0 = *(const bf8_t*)(A + (size_t)(r0 + arow) * 64 + ak0);
    const bf8_t a1 = *(const bf8_t*)(A + (size_t)(r0 + arow) * 64 + 32 + ak0);

    f32x4 acc[8];
#pragma unroll
    for (int i = 0; i < 8; ++i) acc[i] = f32x4{0.f, 0.f, 0.f, 0.f};

#pragma unroll
    for (int tn = 0; tn < 8; ++tn) {
        const unsigned short* bp =
            B + (size_t)(wid * 128 + tn * 16 + (lane & 15)) * 64 + ak0;
        bf8_t b0 = *(const bf8_t*)(bp);
        bf8_t b1 = *(const bf8_t*)(bp + 32);
        acc[tn] = __builtin_amdgcn_mfma_f32_16x16x32_bf16(a0, b0, acc[tn], 0, 0, 0);
        acc[tn] = __builtin_amdgcn_mfma_f32_16x16x32_bf16(a1, b1, acc[tn], 0, 0, 0);
    }

    float elp[2][4], erp[2][4];
#pragma unroll
    for (int hs = 0; hs < 2; ++hs)
#pragma unroll
        for (int r = 0; r < 4; ++r) { elp[hs][r] = 0.f; erp[hs][r] = 0.f; }

#pragma unroll
    for (int tn = 0; tn < 8; ++tn) {
        const int hs = tn >> 2;
        const int col = wid * 128 + tn * 16 + (lane & 15);
        const float av = alf[col], rv = arf[col];
#pragma unroll
        for (int r = 0; r < 4; ++r) {
            elp[hs][r] += acc[tn][r] * av;
            erp[hs][r] += acc[tn][r] * rv;
        }
    }
#pragma unroll
    for (int m = 1; m < 16; m <<= 1) {
#pragma unroll
        for (int hs = 0; hs < 2; ++hs)
#pragma unroll
            for (int r = 0; r < 4; ++r) {
                elp[hs][r] += __shfl_xor(elp[hs][r], m, 64);
                erp[hs][r] += __shfl_xor(erp[hs][r], m, 64);
            }
    }
    if ((lane & 15) == 0) {
        float* elg = el + (size_t)tg * NN * 8;
        float* erg = er + (size_t)tg * NN * 8;
#pragma unroll
        for (int r = 0; r < 4; ++r) {
            const int n = r0 + (lane >> 4) * 4 + r;
            elg[n * 8 + 2 * wid + 0] = elp[0][r];
            elg[n * 8 + 2 * wid + 1] = elp[1][r];
            erg[n * 8 + 2 * wid + 0] = erp[0][r];
            erg[n * 8 + 2 * wid + 1] = erp[1][r];
        }
    }

    __shared__ unsigned short sf[16][512];
#pragma unroll
    for (int tn = 0; tn < 8; ++tn)
#pragma unroll
        for (int r = 0; r < 4; ++r)
            sf[(lane >> 4) * 4 + r][wid * 128 + tn * 16 + (lane & 15)] =
                f2bf(acc[tn][r]);
    __syncthreads();
    unsigned short* fo = fb + (size_t)tg * NN * 512;
#pragma unroll
    for (int s = 0; s < 4; ++s) {
        int ch = tid + s * 256;
        int row = ch >> 6, off = (ch & 63) * 8;
        *(uint4*)(fo + (size_t)(r0 + row) * 512 + off) = *(uint4*)&sf[row][off];
    }
}

// ---------------------------------------------------------------------------
// CSR build, batched over all 4 graphs
// ---------------------------------------------------------------------------
__global__ void zero_kernel(int* __restrict__ count, int* __restrict__ cursor,
                            float* __restrict__ wsum)
{
    int i = blockIdx.x * 256 + threadIdx.x;
    if (i < 4 * NN) { count[i] = 0; cursor[i] = 0; }
    if (i < 4) wsum[i] = 0.f;
}

__global__ void hist_kernel(const int* __restrict__ dst_u,
                            const int* __restrict__ dst_i,
                            int* __restrict__ count)
{
    int g = blockIdx.y;
    int i = blockIdx.x * 256 + threadIdx.x;
    if (i < EE) {
        const int* d = (g < 2 ? dst_u : dst_i) + (size_t)(g & 1) * EE;
        atomicAdd(&count[g * NN + d[i]], 1);
    }
}

__global__ __launch_bounds__(256) void scan1_kernel(
    const int* __restrict__ count, int* __restrict__ tmp,
    int* __restrict__ partials)
{
    const int g = blockIdx.y, tid = threadIdx.x;
    const int i = blockIdx.x * 256 + tid;
    __shared__ int sc[256];
    int v = (i < NN) ? count[g * NN + i] : 0;
    sc[tid] = v;
    __syncthreads();
#pragma unroll
    for (int off = 1; off < 256; off <<= 1) {
        int add = (tid >= off) ? sc[tid - off] : 0;
        __syncthreads();
        sc[tid] += add;
        __syncthreads();
    }
    if (i < NN) tmp[g * NN + i] = sc[tid] - v;
    if (tid == 255) partials[g * 79 + blockIdx.x] = sc[255];
}

// FIXED (round-4 abort root cause): 316 partials > 256 threads — the old
// `if (tid < 316)` guards never covered indices 256..315, leaving bases[]
// as 0xAA poison -> wild roff -> OOB scatter write -> GPU memory fault.
// Stride loops cover all 316 with 256 threads.
__global__ __launch_bounds__(256) void scan2_kernel(
    const int* __restrict__ partials, int* __restrict__ bases)
{
    __shared__ int p[320], bl[320];
    const int tid = threadIdx.x;
    for (int i = tid; i < 316; i += 256) p[i] = partials[i];
    __syncthreads();
    if (tid < 4) {
        int base = 0;
        for (int b = 0; b < 79; ++b) { bl[tid * 79 + b] = base; base += p[tid * 79 + b]; }
    }
    __syncthreads();
    for (int i = tid; i < 316; i += 256) bases[i] = bl[i];
}

__global__ void scan3_kernel(const int* __restrict__ tmp,
                             const int* __restrict__ bases,
                             int* __restrict__ roff)
{
    const int g = blockIdx.y;
    const int i = blockIdx.x * 256 + threadIdx.x;
    if (i < NN) roff[g * (NN + 1) + i] = tmp[g * NN + i] + bases[g * 79 + blockIdx.x];
    if (blockIdx.x == 0 && threadIdx.x == 0) roff[g * (NN + 1) + NN] = EE;
}

__global__ void scatter_kernel(const int* __restrict__ src_u,
                               const int* __restrict__ dst_u,
                               const int* __restrict__ src_i,
                               const int* __restrict__ dst_i,
                               const int* __restrict__ roff,
                               int* __restrict__ cursor,
                               int* __restrict__ csrc)
{
    int g = blockIdx.y;
    int i = blockIdx.x * 256 + threadIdx.x;
    if (i < EE) {
        const int* s = (g < 2 ? src_u : src_i) + (size_t)(g & 1) * EE;
        const int* d = (g < 2 ? dst_u : dst_i) + (size_t)(g & 1) * EE;
        int dd = d[i];
        int pp = atomicAdd(&cursor[g * NN + dd], 1);
        csrc[(size_t)g * EE + roff[g * (NN + 1) + dd] + pp] = s[i];
    }
}

// ---------------------------------------------------------------------------
// agg: one wave per dst node (4 nodes / block). lane: 8 cols (bf16x8, 16B),
// head = lane>>3. One-pass softmax (no max shift: e tiny, alpha identical).
// ---------------------------------------------------------------------------
__global__ __launch_bounds__(256) void agg_kernel(
    const unsigned short* __restrict__ fb,
    const float* __restrict__ el, const float* __restrict__ er,
    const int* __restrict__ roff, const int* __restrict__ csrc,
    const float* __restrict__ bg_u, const float* __restrict__ bg_i,
    unsigned short* __restrict__ zb)
{
    const int tg = blockIdx.y, t = tg >> 1, g = tg & 1;
    const int tid = threadIdx.x, wid = tid >> 6, lane = tid & 63;
    const int n = blockIdx.x * 4 + wid;
    const unsigned short* fg = fb + (size_t)tg * NN * 512;
    const float* elg = el + (size_t)tg * NN * 8;
    const float* erg = er + (size_t)tg * NN * 8;
    const int* ro = roff + (size_t)tg * (NN + 1);
    const int* cs = csrc + (size_t)tg * EE;
    const float* bias = (t ? bg_i : bg_u) + g * 512;

    const int h = lane >> 3, c0 = lane * 8;
    const float ern = erg[n * 8 + h];
    const int beg = ro[n], end = ro[n + 1];

    float s = 0.f;
    float a0 = 0.f, a1 = 0.f, a2 = 0.f, a3 = 0.f, a4 = 0.f, a5 = 0.f, a6 = 0.f, a7 = 0.f;
    for (int e = beg; e < end; ++e) {
        int src = cs[e];
        float x = elg[src * 8 + h] + ern;
        x = (x >= 0.f) ? x : 0.2f * x;
        float ex = __expf(x);
        s += ex;
        uint4 fv = *(const uint4*)(fg + (size_t)src * 512 + c0);
        a0 += ex * bf2f(fv.x & 0xffffu);  a1 += ex * __uint_as_float(fv.x & 0xffff0000u);
        a2 += ex * bf2f(fv.y & 0xffffu);  a3 += ex * __uint_as_float(fv.y & 0xffff0000u);
        a4 += ex * bf2f(fv.z & 0xffffu);  a5 += ex * __uint_as_float(fv.z & 0xffff0000u);
        a6 += ex * bf2f(fv.w & 0xffffu);  a7 += ex * __uint_as_float(fv.w & 0xffff0000u);
    }
    const float inv = 1.f / fmaxf(s, 1e-9f);
    const float4 bA = *(const float4*)(bias + c0);
    const float4 bB = *(const float4*)(bias + c0 + 4);
    float o0 = a0 * inv + bA.x; o0 = o0 > 0.f ? o0 : expm1f(o0);
    float o1 = a1 * inv + bA.y; o1 = o1 > 0.f ? o1 : expm1f(o1);
    float o2 = a2 * inv + bA.z; o2 = o2 > 0.f ? o2 : expm1f(o2);
    float o3 = a3 * inv + bA.w; o3 = o3 > 0.f ? o3 : expm1f(o3);
    float o4 = a4 * inv + bB.x; o4 = o4 > 0.f ? o4 : expm1f(o4);
    float o5 = a5 * inv + bB.y; o5 = o5 > 0.f ? o5 : expm1f(o5);
    float o6 = a6 * inv + bB.z; o6 = o6 > 0.f ? o6 : expm1f(o6);
    float o7 = a7 * inv + bB.w; o7 = o7 > 0.f ? o7 : expm1f(o7);
    uint4 pk;
    pk.x = ((unsigned)f2bf(o1) << 16) | f2bf(o0);
    pk.y = ((unsigned)f2bf(o3) << 16) | f2bf(o2);
    pk.z = ((unsigned)f2bf(o5) << 16) | f2bf(o4);
    pk.w = ((unsigned)f2bf(o7) << 16) | f2bf(o6);
    *(uint4*)(zb + (size_t)tg * NN * 512 + (size_t)n * 512 + c0) = pk;
}

// ---------------------------------------------------------------------------
// sem (MFMA): wsum[tm] += sum over 32-row tile of tanh(z@W1+b1)[c]*v[c]
// ---------------------------------------------------------------------------
__global__ __launch_bounds__(256) void sem_kernel(
    const unsigned short* __restrict__ zb,
    const unsigned short* __restrict__ W1t,
    const float* __restrict__ bs_u, const float* __restrict__ vs_u,
    const float* __restrict__ bs_i, const float* __restrict__ vs_i,
    float* __restrict__ wsum)
{
    const int tm = blockIdx.y, t = tm >> 1;
    const int tid = threadIdx.x, wid = tid >> 6, lane = tid & 63;
    const int r0 = blockIdx.x * 32;
    const unsigned short* Az = zb + (size_t)tm * NN * 512;
    const unsigned short* Bw = W1t + (size_t)t * 128 * 512;
    const float* b1f = t ? bs_i : bs_u;
    const float* vf  = t ? vs_i : vs_u;

    const int arow = lane & 15, ak0 = (lane >> 4) * 8;
    const int col0 = wid * 32 + (lane & 15);
    const unsigned short* a0p = Az + (size_t)(r0 + arow) * 512 + ak0;
    const unsigned short* a1p = a0p + 16 * 512;
    const unsigned short* b0p = Bw + (size_t)col0 * 512 + ak0;
    const unsigned short* b1p = b0p + 16 * 512;

    f32x4 acc00 = f32x4{0.f,0.f,0.f,0.f}, acc01 = acc00, acc10 = acc00, acc11 = acc00;
#pragma unroll 4
    for (int k = 0; k < 512; k += 32) {
        bf8_t a0 = *(const bf8_t*)(a0p + k);
        bf8_t a1 = *(const bf8_t*)(a1p + k);
        bf8_t b0 = *(const bf8_t*)(b0p + k);
        bf8_t b1 = *(const bf8_t*)(b1p + k);
        acc00 = __builtin_amdgcn_mfma_f32_16x16x32_bf16(a0, b0, acc00, 0, 0, 0);
        acc01 = __builtin_amdgcn_mfma_f32_16x16x32_bf16(a0, b1, acc01, 0, 0, 0);
        acc10 = __builtin_amdgcn_mfma_f32_16x16x32_bf16(a1, b0, acc10, 0, 0, 0);
        acc11 = __builtin_amdgcn_mfma_f32_16x16x32_bf16(a1, b1, acc11, 0, 0, 0);
    }

    const float b1c0 = b1f[col0], b1c1 = b1f[col0 + 16];
    const float vc0 = vf[col0],  vc1 = vf[col0 + 16];
    float q = 0.f;
#pragma unroll
    for (int r = 0; r < 4; ++r) {
        q += tanhf(acc00[r] + b1c0) * vc0;
        q += tanhf(acc01[r] + b1c1) * vc1;
        q += tanhf(acc10[r] + b1c0) * vc0;
        q += tanhf(acc11[r] + b1c1) * vc1;
    }
#pragma unroll
    for (int m = 1; m < 64; m <<= 1) q += __shfl_xor(q, m, 64);
    __shared__ float red[4];
    if (lane == 0) red[wid] = q;
    __syncthreads();
    if (tid == 0) atomicAdd(&wsum[tm], red[0] + red[1] + red[2] + red[3]);
}

// ---------------------------------------------------------------------------
// combine: beta = softmax(wsum[2t..]/N); hout = b0*z[2t] + b1*z[2t+1] (fp32)
// ---------------------------------------------------------------------------
__global__ void combine_kernel(const unsigned short* __restrict__ zb,
                               const float* __restrict__ wsum,
                               float* __restrict__ hu, float* __restrict__ hi)
{
    const int t = blockIdx.y;
    const float w0 = wsum[2 * t] * (1.f / (float)NN);
    const float w1 = wsum[2 * t + 1] * (1.f / (float)NN);
    const float m = fmaxf(w0, w1);
    const float e0 = __expf(w0 - m), e1 = __expf(w1 - m);
    const float is = 1.f / (e0 + e1);
    const float be0 = e0 * is, be1 = e1 * is;

    const size_t idx = (size_t)blockIdx.x * 256 + threadIdx.x;
    const unsigned short* z0 = zb + (size_t)(2 * t) * NN * 512 + idx * 8;
    const unsigned short* z1 = zb + (size_t)(2 * t + 1) * NN * 512 + idx * 8;
    float* ho = (t ? hi : hu) + idx * 8;
    uint4 u0 = *(const uint4*)z0;
    uint4 u1 = *(const uint4*)z1;
    float4 oA, oB;
    oA.x = be0 * bf2f(u0.x & 0xffffu) + be1 * bf2f(u1.x & 0xffffu);
    oA.y = be0 * __uint_as_float(u0.x & 0xffff0000u) + be1 * __uint_as_float(u1.x & 0xffff0000u);
    oA.z = be0 * bf2f(u0.y & 0xffffu) + be1 * bf2f(u1.y & 0xffffu);
    oA.w = be0 * __uint_as_float(u0.y & 0xffff0000u) + be1 * __uint_as_float(u1.y & 0xffff0000u);
    oB.x = be0 * bf2f(u0.z & 0xffffu) + be1 * bf2f(u1.z & 0xffffu);
    oB.y = be0 * __uint_as_float(u0.z & 0xffff0000u) + be1 * __uint_as_float(u1.z & 0xffff0000u);
    oB.z = be0 * bf2f(u0.w & 0xffffu) + be1 * bf2f(u1.w & 0xffffu);
    oB.w = be0 * __uint_as_float(u0.w & 0xffff0000u) + be1 * __uint_as_float(u1.w & 0xffff0000u);
    *(float4*)(ho) = oA;
    *(float4*)(ho + 4) = oB;
}

// ---------------------------------------------------------------------------
// score + output assembly
// ---------------------------------------------------------------------------
__global__ __launch_bounds__(128) void score_kernel(
    const float* __restrict__ hu, const float* __restrict__ hi,
    const int* __restrict__ uid, const int* __restrict__ pos,
    const int* __restrict__ neg, float* __restrict__ out)
{
    const int bp  = blockIdx.x;
    const int b   = bp >> 3;
    const int tid = threadIdx.x;
    __shared__ float red[2];

    float* pos_logits = out;
    float* neg_logits = out + 8192;
    float* ue_n       = out + 73728;
    float* pe         = out + 33628160;
    float* ne         = out + 37822464;

    const float4 u4 = ((const float4*)(hu + (size_t)uid[b] * 512))[tid];

    {
        const float4 p4 = ((const float4*)(hi + (size_t)pos[bp] * 512))[tid];
        ((float4*)(pe + (size_t)bp * 512))[tid] = p4;
        float d = u4.x * p4.x + u4.y * p4.y + u4.z * p4.z + u4.w * p4.w;
#pragma unroll
        for (int off = 32; off; off >>= 1) d += __shfl_down(d, off, 64);
        if ((tid & 63) == 0) red[tid >> 6] = d;
        __syncthreads();
        if (tid == 0) pos_logits[bp] = red[0] + red[1];
    }
    for (int k = 0; k < 8; ++k) {
        __syncthreads();
        const size_t row = (size_t)bp * 8 + k;
        const float4 n4 = ((const float4*)(hi + (size_t)neg[row] * 512))[tid];
        ((float4*)(ne   + row * 512))[tid] = n4;
        ((float4*)(ue_n + row * 512))[tid] = u4;
        float d = u4.x * n4.x + u4.y * n4.y + u4.z * n4.z + u4.w * n4.w;
#pragma unroll
        for (int off = 32; off; off >>= 1) d += __shfl_down(d, off, 64);
        if ((tid & 63) == 0) red[tid >> 6] = d;
        __syncthreads();
        if (tid == 0) neg_logits[row] = red[0] + red[1];
    }
}

// ---------------------------------------------------------------------------
extern "C" void kernel_launch(void* const* d_in, const int* in_sizes, int n_in,
                              void* d_out, int out_size, void* d_ws, size_t ws_size,
                              hipStream_t stream)
{
    const float* user_embs = (const float*)d_in[0];
    const float* item_embs = (const float*)d_in[1];
    const float* Wg_u = (const float*)d_in[2];
    const float* al_u = (const float*)d_in[3];
    const float* ar_u = (const float*)d_in[4];
    const float* bg_u = (const float*)d_in[5];
    const float* Ws_u = (const float*)d_in[6];
    const float* bs_u = (const float*)d_in[7];
    const float* vs_u = (const float*)d_in[8];
    const float* Wg_i = (const float*)d_in[9];
    const float* al_i = (const float*)d_in[10];
    const float* ar_i = (const float*)d_in[11];
    const float* bg_i = (const float*)d_in[12];
    const float* Ws_i = (const float*)d_in[13];
    const float* bs_i = (const float*)d_in[14];
    const float* vs_i = (const float*)d_in[15];
    const int* src_u = (const int*)d_in[16];
    const int* dst_u = (const int*)d_in[17];
    const int* src_i = (const int*)d_in[18];
    const int* dst_i = (const int*)d_in[19];
    const int* uid = (const int*)d_in[20];
    const int* pos = (const int*)d_in[21];
    const int* neg = (const int*)d_in[22];

    char* p = (char*)d_ws;
    auto carve = [&](size_t bytes) {
        char* r = p; p += (bytes + 255) & ~(size_t)255; return r;
    };
    unsigned short* fb  = (unsigned short*)carve((size_t)4 * NN * 512 * 2);  // 81.92 MB
    unsigned short* zb  = (unsigned short*)carve((size_t)4 * NN * 512 * 2);  // 81.92 MB
    unsigned short* hb  = (unsigned short*)carve((size_t)2 * NN * 64 * 2);
    unsigned short* Wt  = (unsigned short*)carve((size_t)4 * 512 * 64 * 2);
    unsigned short* W1t = (unsigned short*)carve((size_t)2 * 128 * 512 * 2);
    float* el   = (float*)carve((size_t)4 * NN * 8 * 4);
    float* er   = (float*)carve((size_t)4 * NN * 8 * 4);
    float* wsum = (float*)carve(64);
    int* count    = (int*)carve((size_t)4 * NN * 4);
    int* cursor   = (int*)carve((size_t)4 * NN * 4);
    int* tmp      = (int*)carve((size_t)4 * NN * 4);
    int* roff     = (int*)carve((size_t)4 * (NN + 1) * 4);
    int* partials = (int*)carve(320 * 4);
    int* bases    = (int*)carve(320 * 4);
    int* csrc     = (int*)carve((size_t)4 * EE * 4);
    // hu/hi ALIAS fb: fb (4*NN*512*2 B) is dead after agg_kernel; hu+hi
    // (2*NN*512*4 B) is exactly the same size. combine writes them after
    // sem (which reads only zb). Keeps total ws ~171 MiB.
    float* hu = (float*)fb;
    float* hi = hu + (size_t)NN * 512;

    prep_kernel<<<(2 * NN * 64 + 255) / 256, 256, 0, stream>>>(
        user_embs, item_embs, Wg_u, Wg_i, Ws_u, Ws_i, hb, Wt, W1t);
    zero_kernel<<<(4 * NN + 255) / 256, 256, 0, stream>>>(count, cursor, wsum);
    hist_kernel<<<dim3((EE + 255) / 256, 4), 256, 0, stream>>>(dst_u, dst_i, count);
    scan1_kernel<<<dim3(79, 4), 256, 0, stream>>>(count, tmp, partials);
    scan2_kernel<<<1, 256, 0, stream>>>(partials, bases);
    scan3_kernel<<<dim3(79, 4), 256, 0, stream>>>(tmp, bases, roff);
    scatter_kernel<<<dim3((EE + 255) / 256, 4), 256, 0, stream>>>(
        src_u, dst_u, src_i, dst_i, roff, cursor, csrc);
    fc_kernel<<<dim3(NN / 16, 4), 256, 0, stream>>>(
        hb, Wt, al_u, ar_u, al_i, ar_i, fb, el, er);
    agg_kernel<<<dim3(NN / 4, 4), 256, 0, stream>>>(
        fb, el, er, roff, csrc, bg_u, bg_i, zb);
    sem_kernel<<<dim3(NN / 32, 4), 256, 0, stream>>>(
        zb, W1t, bs_u, vs_u, bs_i, vs_i, wsum);
    combine_kernel<<<dim3(NN * 512 / 8 / 256, 2), 256, 0, stream>>>(zb, wsum, hu, hi);
    score_kernel<<<1024 * 8, 128, 0, stream>>>(hu, hi, uid, pos, neg, (float*)d_out);
}

// Round 9
// 691.820 us; speedup vs baseline: 1.9591x; 1.0368x over previous
//
#include <hip/hip_runtime.h>
#include <hip/hip_bf16.h>
#include <cstddef>

#define NN 20000
#define EE 200000

typedef __attribute__((ext_vector_type(8))) short bf8_t;   // 8 bf16 (4 VGPRs)
typedef __attribute__((ext_vector_type(4))) float f32x4;   // MFMA acc

__device__ __forceinline__ float bf2f(unsigned int lo16) {
    return __uint_as_float(lo16 << 16);
}
__device__ __forceinline__ float hi16f(unsigned int u) {
    return __uint_as_float(u & 0xffff0000u);
}
__device__ __forceinline__ unsigned short f2bf(float f) {   // RNE
    unsigned u = __float_as_uint(f);
    u += 0x7fffu + ((u >> 16) & 1u);
    return (unsigned short)(u >> 16);
}

// ---------------------------------------------------------------------------
// prep: pack h -> bf16, W -> bf16 [col][k], W1 -> bf16 [c][k]; zero CSR bufs
// (zeroing fused here: all writes statically bounded, cannot fault)
// ---------------------------------------------------------------------------
__global__ void prep_kernel(
    const float* __restrict__ user_embs, const float* __restrict__ item_embs,
    const float* __restrict__ Wg_u, const float* __restrict__ Wg_i,
    const float* __restrict__ Ws_u, const float* __restrict__ Ws_i,
    unsigned short* __restrict__ hb,     // [2][NN*64]
    unsigned short* __restrict__ Wt,     // [4][512*64]  (col*64 + k)
    unsigned short* __restrict__ W1t,    // [2][128*512] (c*512 + k)
    int* __restrict__ count, int* __restrict__ cursor,
    float* __restrict__ wsum)
{
    int i = blockIdx.x * 256 + threadIdx.x;
    if (i < 2 * NN * 64) {
        float v = (i < NN * 64) ? user_embs[i] : item_embs[i - NN * 64];
        hb[i] = f2bf(v);
    }
    if (i < 4 * 512 * 64) {
        int tg = i >> 15, rem = i & 32767;
        int col = rem >> 6, k = rem & 63;
        const float* W = (tg < 2 ? Wg_u + tg * 32768 : Wg_i + (tg - 2) * 32768);
        Wt[i] = f2bf(W[k * 512 + col]);
    }
    if (i < 2 * 128 * 512) {
        int t = i >> 16, rem = i & 65535;
        int c = rem >> 9, k = rem & 511;
        const float* Wsrc = t ? Ws_i : Ws_u;
        W1t[i] = f2bf(Wsrc[k * 128 + c]);
    }
    if (i < 4 * NN) { count[i] = 0; cursor[i] = 0; }
    if (i < 4) wsum[i] = 0.f;
}

// ---------------------------------------------------------------------------
// fc (MFMA): f[tg] = h[t] @ W[tg], fused el/er epilogue (round-6, passing)
// ---------------------------------------------------------------------------
__global__ __launch_bounds__(256) void fc_kernel(
    const unsigned short* __restrict__ hb,
    const unsigned short* __restrict__ Wt,
    const float* __restrict__ al_u, const float* __restrict__ ar_u,
    const float* __restrict__ al_i, const float* __restrict__ ar_i,
    unsigned short* __restrict__ fb,     // [4][NN*512] bf16
    float* __restrict__ el, float* __restrict__ er)  // [4][NN*8]
{
    const int tg = blockIdx.y, t = tg >> 1, g = tg & 1;
    const int tid = threadIdx.x, wid = tid >> 6, lane = tid & 63;
    const int r0 = blockIdx.x * 16;
    const unsigned short* A = hb + (size_t)t * NN * 64;
    const unsigned short* B = Wt + (size_t)tg * 512 * 64;
    const float* alf = (t ? al_i : al_u) + g * 512;
    const float* arf = (t ? ar_i : ar_u) + g * 512;

    const int arow = lane & 15, ak0 = (lane >> 4) * 8;
    const bf8_t a0 = *(const bf8_t*)(A + (size_t)(r0 + arow) * 64 + ak0);
    const bf8_t a1 = *(const bf8_t*)(A + (size_t)(r0 + arow) * 64 + 32 + ak0);

    f32x4 acc[8];
#pragma unroll
    for (int i = 0; i < 8; ++i) acc[i] = f32x4{0.f, 0.f, 0.f, 0.f};

#pragma unroll
    for (int tn = 0; tn < 8; ++tn) {
        const unsigned short* bp =
            B + (size_t)(wid * 128 + tn * 16 + (lane & 15)) * 64 + ak0;
        bf8_t b0 = *(const bf8_t*)(bp);
        bf8_t b1 = *(const bf8_t*)(bp + 32);
        acc[tn] = __builtin_amdgcn_mfma_f32_16x16x32_bf16(a0, b0, acc[tn], 0, 0, 0);
        acc[tn] = __builtin_amdgcn_mfma_f32_16x16x32_bf16(a1, b1, acc[tn], 0, 0, 0);
    }

    float elp[2][4], erp[2][4];
#pragma unroll
    for (int hs = 0; hs < 2; ++hs)
#pragma unroll
        for (int r = 0; r < 4; ++r) { elp[hs][r] = 0.f; erp[hs][r] = 0.f; }

#pragma unroll
    for (int tn = 0; tn < 8; ++tn) {
        const int hs = tn >> 2;
        const int col = wid * 128 + tn * 16 + (lane & 15);
        const float av = alf[col], rv = arf[col];
#pragma unroll
        for (int r = 0; r < 4; ++r) {
            elp[hs][r] += acc[tn][r] * av;
            erp[hs][r] += acc[tn][r] * rv;
        }
    }
#pragma unroll
    for (int m = 1; m < 16; m <<= 1) {
#pragma unroll
        for (int hs = 0; hs < 2; ++hs)
#pragma unroll
            for (int r = 0; r < 4; ++r) {
                elp[hs][r] += __shfl_xor(elp[hs][r], m, 64);
                erp[hs][r] += __shfl_xor(erp[hs][r], m, 64);
            }
    }
    if ((lane & 15) == 0) {
        float* elg = el + (size_t)tg * NN * 8;
        float* erg = er + (size_t)tg * NN * 8;
#pragma unroll
        for (int r = 0; r < 4; ++r) {
            const int n = r0 + (lane >> 4) * 4 + r;
            elg[n * 8 + 2 * wid + 0] = elp[0][r];
            elg[n * 8 + 2 * wid + 1] = elp[1][r];
            erg[n * 8 + 2 * wid + 0] = erp[0][r];
            erg[n * 8 + 2 * wid + 1] = erp[1][r];
        }
    }

    __shared__ unsigned short sf[16][512];
#pragma unroll
    for (int tn = 0; tn < 8; ++tn)
#pragma unroll
        for (int r = 0; r < 4; ++r)
            sf[(lane >> 4) * 4 + r][wid * 128 + tn * 16 + (lane & 15)] =
                f2bf(acc[tn][r]);
    __syncthreads();
    unsigned short* fo = fb + (size_t)tg * NN * 512;
#pragma unroll
    for (int s = 0; s < 4; ++s) {
        int ch = tid + s * 256;
        int row = ch >> 6, off = (ch & 63) * 8;
        *(uint4*)(fo + (size_t)(r0 + row) * 512 + off) = *(uint4*)&sf[row][off];
    }
}

// ---------------------------------------------------------------------------
// CSR build (round-6 proven 3-kernel scan; scan2 has the strided 316 fix)
// ---------------------------------------------------------------------------
__global__ void hist_kernel(const int* __restrict__ dst_u,
                            const int* __restrict__ dst_i,
                            int* __restrict__ count)
{
    int g = blockIdx.y;
    int i = blockIdx.x * 256 + threadIdx.x;
    if (i < EE) {
        const int* d = (g < 2 ? dst_u : dst_i) + (size_t)(g & 1) * EE;
        atomicAdd(&count[g * NN + d[i]], 1);
    }
}

__global__ __launch_bounds__(256) void scan1_kernel(
    const int* __restrict__ count, int* __restrict__ tmp,
    int* __restrict__ partials)
{
    const int g = blockIdx.y, tid = threadIdx.x;
    const int i = blockIdx.x * 256 + tid;
    __shared__ int sc[256];
    int v = (i < NN) ? count[g * NN + i] : 0;
    sc[tid] = v;
    __syncthreads();
#pragma unroll
    for (int off = 1; off < 256; off <<= 1) {
        int add = (tid >= off) ? sc[tid - off] : 0;
        __syncthreads();
        sc[tid] += add;
        __syncthreads();
    }
    if (i < NN) tmp[g * NN + i] = sc[tid] - v;
    if (tid == 255) partials[g * 79 + blockIdx.x] = sc[255];
}

__global__ __launch_bounds__(256) void scan2_kernel(
    const int* __restrict__ partials, int* __restrict__ bases)
{
    __shared__ int p[320], bl[320];
    const int tid = threadIdx.x;
    for (int i = tid; i < 316; i += 256) p[i] = partials[i];
    __syncthreads();
    if (tid < 4) {
        int base = 0;
        for (int b = 0; b < 79; ++b) { bl[tid * 79 + b] = base; base += p[tid * 79 + b]; }
    }
    __syncthreads();
    for (int i = tid; i < 316; i += 256) bases[i] = bl[i];
}

__global__ void scan3_kernel(const int* __restrict__ tmp,
                             const int* __restrict__ bases,
                             int* __restrict__ roff)
{
    const int g = blockIdx.y;
    const int i = blockIdx.x * 256 + threadIdx.x;
    if (i < NN) roff[g * (NN + 1) + i] = tmp[g * NN + i] + bases[g * 79 + blockIdx.x];
    if (blockIdx.x == 0 && threadIdx.x == 0) roff[g * (NN + 1) + NN] = EE;
}

__global__ void scatter_kernel(const int* __restrict__ src_u,
                               const int* __restrict__ dst_u,
                               const int* __restrict__ src_i,
                               const int* __restrict__ dst_i,
                               const int* __restrict__ roff,
                               int* __restrict__ cursor,
                               int* __restrict__ csrc)
{
    int g = blockIdx.y;
    int i = blockIdx.x * 256 + threadIdx.x;
    if (i < EE) {
        const int* s = (g < 2 ? src_u : src_i) + (size_t)(g & 1) * EE;
        const int* d = (g < 2 ? dst_u : dst_i) + (size_t)(g & 1) * EE;
        int dd = d[i];
        int pp = atomicAdd(&cursor[g * NN + dd], 1);
        csrc[(size_t)g * EE + roff[g * (NN + 1) + dd] + pp] = s[i];
    }
}

// ---------------------------------------------------------------------------
// agg (round-6 proven serial-loop version)
// ---------------------------------------------------------------------------
__global__ __launch_bounds__(256) void agg_kernel(
    const unsigned short* __restrict__ fb,
    const float* __restrict__ el, const float* __restrict__ er,
    const int* __restrict__ roff, const int* __restrict__ csrc,
    const float* __restrict__ bg_u, const float* __restrict__ bg_i,
    unsigned short* __restrict__ zb)
{
    const int tg = blockIdx.y, t = tg >> 1, g = tg & 1;
    const int tid = threadIdx.x, wid = tid >> 6, lane = tid & 63;
    const int n = blockIdx.x * 4 + wid;
    const unsigned short* fg = fb + (size_t)tg * NN * 512;
    const float* elg = el + (size_t)tg * NN * 8;
    const float* erg = er + (size_t)tg * NN * 8;
    const int* ro = roff + (size_t)tg * (NN + 1);
    const int* cs = csrc + (size_t)tg * EE;
    const float* bias = (t ? bg_i : bg_u) + g * 512;

    const int h = lane >> 3, c0 = lane * 8;
    const float ern = erg[n * 8 + h];
    const int beg = ro[n], end = ro[n + 1];

    float s = 0.f;
    float a0 = 0.f, a1 = 0.f, a2 = 0.f, a3 = 0.f, a4 = 0.f, a5 = 0.f, a6 = 0.f, a7 = 0.f;
    for (int e = beg; e < end; ++e) {
        int src = cs[e];
        float x = elg[src * 8 + h] + ern;
        x = (x >= 0.f) ? x : 0.2f * x;
        float ex = __expf(x);
        s += ex;
        uint4 fv = *(const uint4*)(fg + (size_t)src * 512 + c0);
        a0 += ex * bf2f(fv.x & 0xffffu);  a1 += ex * hi16f(fv.x);
        a2 += ex * bf2f(fv.y & 0xffffu);  a3 += ex * hi16f(fv.y);
        a4 += ex * bf2f(fv.z & 0xffffu);  a5 += ex * hi16f(fv.z);
        a6 += ex * bf2f(fv.w & 0xffffu);  a7 += ex * hi16f(fv.w);
    }
    const float inv = 1.f / fmaxf(s, 1e-9f);
    const float4 bA = *(const float4*)(bias + c0);
    const float4 bB = *(const float4*)(bias + c0 + 4);
    float o0 = a0 * inv + bA.x; o0 = o0 > 0.f ? o0 : expm1f(o0);
    float o1 = a1 * inv + bA.y; o1 = o1 > 0.f ? o1 : expm1f(o1);
    float o2 = a2 * inv + bA.z; o2 = o2 > 0.f ? o2 : expm1f(o2);
    float o3 = a3 * inv + bA.w; o3 = o3 > 0.f ? o3 : expm1f(o3);
    float o4 = a4 * inv + bB.x; o4 = o4 > 0.f ? o4 : expm1f(o4);
    float o5 = a5 * inv + bB.y; o5 = o5 > 0.f ? o5 : expm1f(o5);
    float o6 = a6 * inv + bB.z; o6 = o6 > 0.f ? o6 : expm1f(o6);
    float o7 = a7 * inv + bB.w; o7 = o7 > 0.f ? o7 : expm1f(o7);
    uint4 pk;
    pk.x = ((unsigned)f2bf(o1) << 16) | f2bf(o0);
    pk.y = ((unsigned)f2bf(o3) << 16) | f2bf(o2);
    pk.z = ((unsigned)f2bf(o5) << 16) | f2bf(o4);
    pk.w = ((unsigned)f2bf(o7) << 16) | f2bf(o6);
    *(uint4*)(zb + (size_t)tg * NN * 512 + (size_t)n * 512 + c0) = pk;
}

// ---------------------------------------------------------------------------
// sem (MFMA): wsum[tm] += sum over 32-row tile of tanh(z@W1+b1)[c]*v[c]
// ---------------------------------------------------------------------------
__global__ __launch_bounds__(256) void sem_kernel(
    const unsigned short* __restrict__ zb,
    const unsigned short* __restrict__ W1t,
    const float* __restrict__ bs_u, const float* __restrict__ vs_u,
    const float* __restrict__ bs_i, const float* __restrict__ vs_i,
    float* __restrict__ wsum)
{
    const int tm = blockIdx.y, t = tm >> 1;
    const int tid = threadIdx.x, wid = tid >> 6, lane = tid & 63;
    const int r0 = blockIdx.x * 32;
    const unsigned short* Az = zb + (size_t)tm * NN * 512;
    const unsigned short* Bw = W1t + (size_t)t * 128 * 512;
    const float* b1f = t ? bs_i : bs_u;
    const float* vf  = t ? vs_i : vs_u;

    const int arow = lane & 15, ak0 = (lane >> 4) * 8;
    const int col0 = wid * 32 + (lane & 15);
    const unsigned short* a0p = Az + (size_t)(r0 + arow) * 512 + ak0;
    const unsigned short* a1p = a0p + 16 * 512;
    const unsigned short* b0p = Bw + (size_t)col0 * 512 + ak0;
    const unsigned short* b1p = b0p + 16 * 512;

    f32x4 acc00 = f32x4{0.f,0.f,0.f,0.f}, acc01 = acc00, acc10 = acc00, acc11 = acc00;
#pragma unroll 4
    for (int k = 0; k < 512; k += 32) {
        bf8_t a0 = *(const bf8_t*)(a0p + k);
        bf8_t a1 = *(const bf8_t*)(a1p + k);
        bf8_t b0 = *(const bf8_t*)(b0p + k);
        bf8_t b1 = *(const bf8_t*)(b1p + k);
        acc00 = __builtin_amdgcn_mfma_f32_16x16x32_bf16(a0, b0, acc00, 0, 0, 0);
        acc01 = __builtin_amdgcn_mfma_f32_16x16x32_bf16(a0, b1, acc01, 0, 0, 0);
        acc10 = __builtin_amdgcn_mfma_f32_16x16x32_bf16(a1, b0, acc10, 0, 0, 0);
        acc11 = __builtin_amdgcn_mfma_f32_16x16x32_bf16(a1, b1, acc11, 0, 0, 0);
    }

    const float b1c0 = b1f[col0], b1c1 = b1f[col0 + 16];
    const float vc0 = vf[col0],  vc1 = vf[col0 + 16];
    float q = 0.f;
#pragma unroll
    for (int r = 0; r < 4; ++r) {
        q += tanhf(acc00[r] + b1c0) * vc0;
        q += tanhf(acc01[r] + b1c1) * vc1;
        q += tanhf(acc10[r] + b1c0) * vc0;
        q += tanhf(acc11[r] + b1c1) * vc1;
    }
#pragma unroll
    for (int m = 1; m < 64; m <<= 1) q += __shfl_xor(q, m, 64);
    __shared__ float red[4];
    if (lane == 0) red[wid] = q;
    __syncthreads();
    if (tid == 0) atomicAdd(&wsum[tm], red[0] + red[1] + red[2] + red[3]);
}

// ---------------------------------------------------------------------------
// score: ONE WAVE per (b,p); combines beta*z in-register from zb (identical
// fp32 expression the old combine kernel wrote -> bitwise-same outputs).
// All indices input-bounded -> cannot generate an OOB address.
// ---------------------------------------------------------------------------
__device__ __forceinline__ void comb8(uint4 q0, uint4 q1, float b0, float b1,
                                      float* __restrict__ o)
{
    o[0] = b0 * bf2f(q0.x & 0xffffu) + b1 * bf2f(q1.x & 0xffffu);
    o[1] = b0 * hi16f(q0.x)          + b1 * hi16f(q1.x);
    o[2] = b0 * bf2f(q0.y & 0xffffu) + b1 * bf2f(q1.y & 0xffffu);
    o[3] = b0 * hi16f(q0.y)          + b1 * hi16f(q1.y);
    o[4] = b0 * bf2f(q0.z & 0xffffu) + b1 * bf2f(q1.z & 0xffffu);
    o[5] = b0 * hi16f(q0.z)          + b1 * hi16f(q1.z);
    o[6] = b0 * bf2f(q0.w & 0xffffu) + b1 * bf2f(q1.w & 0xffffu);
    o[7] = b0 * hi16f(q0.w)          + b1 * hi16f(q1.w);
}

__global__ __launch_bounds__(64) void score_kernel(
    const unsigned short* __restrict__ zb,
    const float* __restrict__ wsum,
    const int* __restrict__ uid, const int* __restrict__ pos,
    const int* __restrict__ neg, float* __restrict__ out)
{
    const int bp = blockIdx.x, b = bp >> 3;
    const int lane = threadIdx.x;
    const int c0 = lane * 8;

    const float wu0 = wsum[0] * (1.f / (float)NN), wu1 = wsum[1] * (1.f / (float)NN);
    const float mu = fmaxf(wu0, wu1);
    const float eu0 = __expf(wu0 - mu), eu1 = __expf(wu1 - mu);
    const float su = 1.f / (eu0 + eu1);
    const float bu0 = eu0 * su, bu1 = eu1 * su;
    const float wi0 = wsum[2] * (1.f / (float)NN), wi1 = wsum[3] * (1.f / (float)NN);
    const float mi = fmaxf(wi0, wi1);
    const float ei0 = __expf(wi0 - mi), ei1 = __expf(wi1 - mi);
    const float si = 1.f / (ei0 + ei1);
    const float bi0 = ei0 * si, bi1 = ei1 * si;

    const unsigned short* zu0 = zb;
    const unsigned short* zu1 = zb + (size_t)NN * 512;
    const unsigned short* zi0 = zb + (size_t)2 * NN * 512;
    const unsigned short* zi1 = zb + (size_t)3 * NN * 512;

    float* pos_logits = out;
    float* neg_logits = out + 8192;
    float* ue_n       = out + 73728;
    float* pe         = out + 33628160;
    float* ne         = out + 37822464;

    float u[8];
    {
        const size_t off = (size_t)uid[b] * 512 + c0;
        comb8(*(const uint4*)(zu0 + off), *(const uint4*)(zu1 + off), bu0, bu1, u);
    }

    // positive
    {
        const size_t off = (size_t)pos[bp] * 512 + c0;
        float pv[8];
        comb8(*(const uint4*)(zi0 + off), *(const uint4*)(zi1 + off), bi0, bi1, pv);
        float* pr = pe + (size_t)bp * 512 + c0;
        *(float4*)(pr)     = make_float4(pv[0], pv[1], pv[2], pv[3]);
        *(float4*)(pr + 4) = make_float4(pv[4], pv[5], pv[6], pv[7]);
        float d = u[0]*pv[0] + u[1]*pv[1] + u[2]*pv[2] + u[3]*pv[3]
                + u[4]*pv[4] + u[5]*pv[5] + u[6]*pv[6] + u[7]*pv[7];
#pragma unroll
        for (int off2 = 32; off2; off2 >>= 1) d += __shfl_down(d, off2, 64);
        if (lane == 0) pos_logits[bp] = d;
    }

    // negatives
    for (int k = 0; k < 8; ++k) {
        const size_t row = (size_t)bp * 8 + k;
        const size_t off = (size_t)neg[row] * 512 + c0;
        float nv[8];
        comb8(*(const uint4*)(zi0 + off), *(const uint4*)(zi1 + off), bi0, bi1, nv);
        float* nr = ne + row * 512 + c0;
        *(float4*)(nr)     = make_float4(nv[0], nv[1], nv[2], nv[3]);
        *(float4*)(nr + 4) = make_float4(nv[4], nv[5], nv[6], nv[7]);
        float* ur = ue_n + row * 512 + c0;
        *(float4*)(ur)     = make_float4(u[0], u[1], u[2], u[3]);
        *(float4*)(ur + 4) = make_float4(u[4], u[5], u[6], u[7]);
        float d = u[0]*nv[0] + u[1]*nv[1] + u[2]*nv[2] + u[3]*nv[3]
                + u[4]*nv[4] + u[5]*nv[5] + u[6]*nv[6] + u[7]*nv[7];
#pragma unroll
        for (int off2 = 32; off2; off2 >>= 1) d += __shfl_down(d, off2, 64);
        if (lane == 0) neg_logits[row] = d;
    }
}

// ---------------------------------------------------------------------------
extern "C" void kernel_launch(void* const* d_in, const int* in_sizes, int n_in,
                              void* d_out, int out_size, void* d_ws, size_t ws_size,
                              hipStream_t stream)
{
    const float* user_embs = (const float*)d_in[0];
    const float* item_embs = (const float*)d_in[1];
    const float* Wg_u = (const float*)d_in[2];
    const float* al_u = (const float*)d_in[3];
    const float* ar_u = (const float*)d_in[4];
    const float* bg_u = (const float*)d_in[5];
    const float* Ws_u = (const float*)d_in[6];
    const float* bs_u = (const float*)d_in[7];
    const float* vs_u = (const float*)d_in[8];
    const float* Wg_i = (const float*)d_in[9];
    const float* al_i = (const float*)d_in[10];
    const float* ar_i = (const float*)d_in[11];
    const float* bg_i = (const float*)d_in[12];
    const float* Ws_i = (const float*)d_in[13];
    const float* bs_i = (const float*)d_in[14];
    const float* vs_i = (const float*)d_in[15];
    const int* src_u = (const int*)d_in[16];
    const int* dst_u = (const int*)d_in[17];
    const int* src_i = (const int*)d_in[18];
    const int* dst_i = (const int*)d_in[19];
    const int* uid = (const int*)d_in[20];
    const int* pos = (const int*)d_in[21];
    const int* neg = (const int*)d_in[22];

    char* p = (char*)d_ws;
    auto carve = [&](size_t bytes) {
        char* r = p; p += (bytes + 255) & ~(size_t)255; return r;
    };
    unsigned short* fb  = (unsigned short*)carve((size_t)4 * NN * 512 * 2);  // 81.92 MB
    unsigned short* zb  = (unsigned short*)carve((size_t)4 * NN * 512 * 2);  // 81.92 MB
    unsigned short* hb  = (unsigned short*)carve((size_t)2 * NN * 64 * 2);
    unsigned short* Wt  = (unsigned short*)carve((size_t)4 * 512 * 64 * 2);
    unsigned short* W1t = (unsigned short*)carve((size_t)2 * 128 * 512 * 2);
    float* el   = (float*)carve((size_t)4 * NN * 8 * 4);
    float* er   = (float*)carve((size_t)4 * NN * 8 * 4);
    float* wsum = (float*)carve(64);
    int* count    = (int*)carve((size_t)4 * NN * 4);
    int* cursor   = (int*)carve((size_t)4 * NN * 4);
    int* tmp      = (int*)carve((size_t)4 * NN * 4);
    int* roff     = (int*)carve((size_t)4 * (NN + 1) * 4);
    int* partials = (int*)carve(320 * 4);
    int* bases    = (int*)carve(320 * 4);
    int* csrc     = (int*)carve((size_t)4 * EE * 4);

    prep_kernel<<<(2 * NN * 64 + 255) / 256, 256, 0, stream>>>(
        user_embs, item_embs, Wg_u, Wg_i, Ws_u, Ws_i, hb, Wt, W1t,
        count, cursor, wsum);
    hist_kernel<<<dim3((EE + 255) / 256, 4), 256, 0, stream>>>(dst_u, dst_i, count);
    scan1_kernel<<<dim3(79, 4), 256, 0, stream>>>(count, tmp, partials);
    scan2_kernel<<<1, 256, 0, stream>>>(partials, bases);
    scan3_kernel<<<dim3(79, 4), 256, 0, stream>>>(tmp, bases, roff);
    scatter_kernel<<<dim3((EE + 255) / 256, 4), 256, 0, stream>>>(
        src_u, dst_u, src_i, dst_i, roff, cursor, csrc);
    fc_kernel<<<dim3(NN / 16, 4), 256, 0, stream>>>(
        hb, Wt, al_u, ar_u, al_i, ar_i, fb, el, er);
    agg_kernel<<<dim3(NN / 4, 4), 256, 0, stream>>>(
        fb, el, er, roff, csrc, bg_u, bg_i, zb);
    sem_kernel<<<dim3(NN / 32, 4), 256, 0, stream>>>(
        zb, W1t, bs_u, vs_u, bs_i, vs_i, wsum);
    score_kernel<<<1024 * 8, 64, 0, stream>>>(zb, wsum, uid, pos, neg, (float*)d_out);
}

// Round 11
// 690.007 us; speedup vs baseline: 1.9642x; 1.0026x over previous
//
#include <hip/hip_runtime.h>
#include <hip/hip_bf16.h>
#include <cstddef>

#define NN 20000
#define EE 200000

typedef __attribute__((ext_vector_type(8))) short bf8_t;   // 8 bf16 (4 VGPRs)
typedef __attribute__((ext_vector_type(4))) float f32x4;   // MFMA acc

__device__ __forceinline__ float bf2f(unsigned int lo16) {
    return __uint_as_float(lo16 << 16);
}
__device__ __forceinline__ float hi16f(unsigned int u) {
    return __uint_as_float(u & 0xffff0000u);
}
__device__ __forceinline__ unsigned short f2bf(float f) {   // RNE
    unsigned u = __float_as_uint(f);
    u += 0x7fffu + ((u >> 16) & 1u);
    return (unsigned short)(u >> 16);
}

// ---------------------------------------------------------------------------
// prep: pack h -> bf16, W -> bf16 [col][k], W1 -> bf16 [c][k]; zero CSR bufs
// ---------------------------------------------------------------------------
__global__ void prep_kernel(
    const float* __restrict__ user_embs, const float* __restrict__ item_embs,
    const float* __restrict__ Wg_u, const float* __restrict__ Wg_i,
    const float* __restrict__ Ws_u, const float* __restrict__ Ws_i,
    unsigned short* __restrict__ hb,     // [2][NN*64]
    unsigned short* __restrict__ Wt,     // [4][512*64]  (col*64 + k)
    unsigned short* __restrict__ W1t,    // [2][128*512] (c*512 + k)
    int* __restrict__ count, int* __restrict__ cursor,
    float* __restrict__ wsum)
{
    int i = blockIdx.x * 256 + threadIdx.x;
    if (i < 2 * NN * 64) {
        float v = (i < NN * 64) ? user_embs[i] : item_embs[i - NN * 64];
        hb[i] = f2bf(v);
    }
    if (i < 4 * 512 * 64) {
        int tg = i >> 15, rem = i & 32767;
        int col = rem >> 6, k = rem & 63;
        const float* W = (tg < 2 ? Wg_u + tg * 32768 : Wg_i + (tg - 2) * 32768);
        Wt[i] = f2bf(W[k * 512 + col]);
    }
    if (i < 2 * 128 * 512) {
        int t = i >> 16, rem = i & 65535;
        int c = rem >> 9, k = rem & 511;
        const float* Wsrc = t ? Ws_i : Ws_u;
        W1t[i] = f2bf(Wsrc[k * 128 + c]);
    }
    if (i < 4 * NN) { count[i] = 0; cursor[i] = 0; }
    if (i < 4) wsum[i] = 0.f;
}

// ---------------------------------------------------------------------------
// hist
// ---------------------------------------------------------------------------
__global__ void hist_kernel(const int* __restrict__ dst_u,
                            const int* __restrict__ dst_i,
                            int* __restrict__ count)
{
    int g = blockIdx.y;
    int i = blockIdx.x * 256 + threadIdx.x;
    if (i < EE) {
        const int* d = (g < 2 ? dst_u : dst_i) + (size_t)(g & 1) * EE;
        atomicAdd(&count[g * NN + d[i]], 1);
    }
}

// ---------------------------------------------------------------------------
// fused scan: 1 block per graph, 1024 thr, 20 elems/thr local prefix +
// Hillis-Steele block scan (read / barrier / write / barrier — race-free).
// Replaces scan1+scan2+scan3 (3 launches -> 1).
// ---------------------------------------------------------------------------
__global__ __launch_bounds__(1024) void scan_kernel(
    const int* __restrict__ count, int* __restrict__ roff)
{
    const int g = blockIdx.x, tid = threadIdx.x;
    __shared__ int sc[1024];
    int loc[20];
    int s = 0;
    const int base = tid * 20;
#pragma unroll
    for (int j = 0; j < 20; ++j) {
        int idx = base + j;
        int v = (idx < NN) ? count[g * NN + idx] : 0;
        loc[j] = s;               // thread-local exclusive prefix
        s += v;
    }
    sc[tid] = s;
    __syncthreads();
    for (int off = 1; off < 1024; off <<= 1) {
        int add = (tid >= off) ? sc[tid - off] : 0;
        __syncthreads();
        sc[tid] += add;
        __syncthreads();
    }
    const int myoff = tid ? sc[tid - 1] : 0;
#pragma unroll
    for (int j = 0; j < 20; ++j) {
        int idx = base + j;
        if (idx < NN) roff[g * (NN + 1) + idx] = myoff + loc[j];
    }
    if (tid == 1023) roff[g * (NN + 1) + NN] = sc[1023];   // == EE
}

// ---------------------------------------------------------------------------
// scatter ∥ fc merged: independent work (scatter needs scan; fc needs prep),
// one launch, block-uniform branch. bx<782 -> scatter, else fc row-block.
// ---------------------------------------------------------------------------
__global__ __launch_bounds__(256) void scatter_fc_kernel(
    const int* __restrict__ src_u, const int* __restrict__ dst_u,
    const int* __restrict__ src_i, const int* __restrict__ dst_i,
    const int* __restrict__ roff, int* __restrict__ cursor,
    int* __restrict__ csrc,
    const unsigned short* __restrict__ hb,
    const unsigned short* __restrict__ Wt,
    const float* __restrict__ al_u, const float* __restrict__ ar_u,
    const float* __restrict__ al_i, const float* __restrict__ ar_i,
    unsigned short* __restrict__ fb,
    float* __restrict__ el, float* __restrict__ er)
{
    __shared__ unsigned short sf[16][512];

    if (blockIdx.x < 782) {
        // ---- scatter (round-9 proven) ----
        int g = blockIdx.y;
        int i = blockIdx.x * 256 + threadIdx.x;
        if (i < EE) {
            const int* s = (g < 2 ? src_u : src_i) + (size_t)(g & 1) * EE;
            const int* d = (g < 2 ? dst_u : dst_i) + (size_t)(g & 1) * EE;
            int dd = d[i];
            int pp = atomicAdd(&cursor[g * NN + dd], 1);
            csrc[(size_t)g * EE + roff[g * (NN + 1) + dd] + pp] = s[i];
        }
        return;
    }

    // ---- fc (round-9 proven, byte-identical arithmetic) ----
    const int tg = blockIdx.y, t = tg >> 1, g = tg & 1;
    const int tid = threadIdx.x, wid = tid >> 6, lane = tid & 63;
    const int r0 = (blockIdx.x - 782) * 16;
    const unsigned short* A = hb + (size_t)t * NN * 64;
    const unsigned short* B = Wt + (size_t)tg * 512 * 64;
    const float* alf = (t ? al_i : al_u) + g * 512;
    const float* arf = (t ? ar_i : ar_u) + g * 512;

    const int arow = lane & 15, ak0 = (lane >> 4) * 8;
    const bf8_t a0 = *(const bf8_t*)(A + (size_t)(r0 + arow) * 64 + ak0);
    const bf8_t a1 = *(const bf8_t*)(A + (size_t)(r0 + arow) * 64 + 32 + ak0);

    f32x4 acc[8];
#pragma unroll
    for (int i = 0; i < 8; ++i) acc[i] = f32x4{0.f, 0.f, 0.f, 0.f};

#pragma unroll
    for (int tn = 0; tn < 8; ++tn) {
        const unsigned short* bp =
            B + (size_t)(wid * 128 + tn * 16 + (lane & 15)) * 64 + ak0;
        bf8_t b0 = *(const bf8_t*)(bp);
        bf8_t b1 = *(const bf8_t*)(bp + 32);
        acc[tn] = __builtin_amdgcn_mfma_f32_16x16x32_bf16(a0, b0, acc[tn], 0, 0, 0);
        acc[tn] = __builtin_amdgcn_mfma_f32_16x16x32_bf16(a1, b1, acc[tn], 0, 0, 0);
    }

    float elp[2][4], erp[2][4];
#pragma unroll
    for (int hs = 0; hs < 2; ++hs)
#pragma unroll
        for (int r = 0; r < 4; ++r) { elp[hs][r] = 0.f; erp[hs][r] = 0.f; }

#pragma unroll
    for (int tn = 0; tn < 8; ++tn) {
        const int hs = tn >> 2;
        const int col = wid * 128 + tn * 16 + (lane & 15);
        const float av = alf[col], rv = arf[col];
#pragma unroll
        for (int r = 0; r < 4; ++r) {
            elp[hs][r] += acc[tn][r] * av;
            erp[hs][r] += acc[tn][r] * rv;
        }
    }
#pragma unroll
    for (int m = 1; m < 16; m <<= 1) {
#pragma unroll
        for (int hs = 0; hs < 2; ++hs)
#pragma unroll
            for (int r = 0; r < 4; ++r) {
                elp[hs][r] += __shfl_xor(elp[hs][r], m, 64);
                erp[hs][r] += __shfl_xor(erp[hs][r], m, 64);
            }
    }
    if ((lane & 15) == 0) {
        float* elg = el + (size_t)tg * NN * 8;
        float* erg = er + (size_t)tg * NN * 8;
#pragma unroll
        for (int r = 0; r < 4; ++r) {
            const int n = r0 + (lane >> 4) * 4 + r;
            elg[n * 8 + 2 * wid + 0] = elp[0][r];
            elg[n * 8 + 2 * wid + 1] = elp[1][r];
            erg[n * 8 + 2 * wid + 0] = erp[0][r];
            erg[n * 8 + 2 * wid + 1] = erp[1][r];
        }
    }

#pragma unroll
    for (int tn = 0; tn < 8; ++tn)
#pragma unroll
        for (int r = 0; r < 4; ++r)
            sf[(lane >> 4) * 4 + r][wid * 128 + tn * 16 + (lane & 15)] =
                f2bf(acc[tn][r]);
    __syncthreads();
    unsigned short* fo = fb + (size_t)tg * NN * 512;
#pragma unroll
    for (int s = 0; s < 4; ++s) {
        int ch = tid + s * 256;
        int row = ch >> 6, off = (ch & 63) * 8;
        *(uint4*)(fo + (size_t)(r0 + row) * 512 + off) = *(uint4*)&sf[row][off];
    }
}

// ---------------------------------------------------------------------------
// agg (round-9 proven serial-loop version — unchanged)
// ---------------------------------------------------------------------------
__global__ __launch_bounds__(256) void agg_kernel(
    const unsigned short* __restrict__ fb,
    const float* __restrict__ el, const float* __restrict__ er,
    const int* __restrict__ roff, const int* __restrict__ csrc,
    const float* __restrict__ bg_u, const float* __restrict__ bg_i,
    unsigned short* __restrict__ zb)
{
    const int tg = blockIdx.y, t = tg >> 1, g = tg & 1;
    const int tid = threadIdx.x, wid = tid >> 6, lane = tid & 63;
    const int n = blockIdx.x * 4 + wid;
    const unsigned short* fg = fb + (size_t)tg * NN * 512;
    const float* elg = el + (size_t)tg * NN * 8;
    const float* erg = er + (size_t)tg * NN * 8;
    const int* ro = roff + (size_t)tg * (NN + 1);
    const int* cs = csrc + (size_t)tg * EE;
    const float* bias = (t ? bg_i : bg_u) + g * 512;

    const int h = lane >> 3, c0 = lane * 8;
    const float ern = erg[n * 8 + h];
    const int beg = ro[n], end = ro[n + 1];

    float s = 0.f;
    float a0 = 0.f, a1 = 0.f, a2 = 0.f, a3 = 0.f, a4 = 0.f, a5 = 0.f, a6 = 0.f, a7 = 0.f;
    for (int e = beg; e < end; ++e) {
        int src = cs[e];
        float x = elg[src * 8 + h] + ern;
        x = (x >= 0.f) ? x : 0.2f * x;
        float ex = __expf(x);
        s += ex;
        uint4 fv = *(const uint4*)(fg + (size_t)src * 512 + c0);
        a0 += ex * bf2f(fv.x & 0xffffu);  a1 += ex * hi16f(fv.x);
        a2 += ex * bf2f(fv.y & 0xffffu);  a3 += ex * hi16f(fv.y);
        a4 += ex * bf2f(fv.z & 0xffffu);  a5 += ex * hi16f(fv.z);
        a6 += ex * bf2f(fv.w & 0xffffu);  a7 += ex * hi16f(fv.w);
    }
    const float inv = 1.f / fmaxf(s, 1e-9f);
    const float4 bA = *(const float4*)(bias + c0);
    const float4 bB = *(const float4*)(bias + c0 + 4);
    float o0 = a0 * inv + bA.x; o0 = o0 > 0.f ? o0 : expm1f(o0);
    float o1 = a1 * inv + bA.y; o1 = o1 > 0.f ? o1 : expm1f(o1);
    float o2 = a2 * inv + bA.z; o2 = o2 > 0.f ? o2 : expm1f(o2);
    float o3 = a3 * inv + bA.w; o3 = o3 > 0.f ? o3 : expm1f(o3);
    float o4 = a4 * inv + bB.x; o4 = o4 > 0.f ? o4 : expm1f(o4);
    float o5 = a5 * inv + bB.y; o5 = o5 > 0.f ? o5 : expm1f(o5);
    float o6 = a6 * inv + bB.z; o6 = o6 > 0.f ? o6 : expm1f(o6);
    float o7 = a7 * inv + bB.w; o7 = o7 > 0.f ? o7 : expm1f(o7);
    uint4 pk;
    pk.x = ((unsigned)f2bf(o1) << 16) | f2bf(o0);
    pk.y = ((unsigned)f2bf(o3) << 16) | f2bf(o2);
    pk.z = ((unsigned)f2bf(o5) << 16) | f2bf(o4);
    pk.w = ((unsigned)f2bf(o7) << 16) | f2bf(o6);
    *(uint4*)(zb + (size_t)tg * NN * 512 + (size_t)n * 512 + c0) = pk;
}

// ---------------------------------------------------------------------------
// sem (MFMA): wsum[tm] += sum over 32-row tile of tanh(z@W1+b1)[c]*v[c]
// ---------------------------------------------------------------------------
__global__ __launch_bounds__(256) void sem_kernel(
    const unsigned short* __restrict__ zb,
    const unsigned short* __restrict__ W1t,
    const float* __restrict__ bs_u, const float* __restrict__ vs_u,
    const float* __restrict__ bs_i, const float* __restrict__ vs_i,
    float* __restrict__ wsum)
{
    const int tm = blockIdx.y, t = tm >> 1;
    const int tid = threadIdx.x, wid = tid >> 6, lane = tid & 63;
    const int r0 = blockIdx.x * 32;
    const unsigned short* Az = zb + (size_t)tm * NN * 512;
    const unsigned short* Bw = W1t + (size_t)t * 128 * 512;
    const float* b1f = t ? bs_i : bs_u;
    const float* vf  = t ? vs_i : vs_u;

    const int arow = lane & 15, ak0 = (lane >> 4) * 8;
    const int col0 = wid * 32 + (lane & 15);
    const unsigned short* a0p = Az + (size_t)(r0 + arow) * 512 + ak0;
    const unsigned short* a1p = a0p + 16 * 512;
    const unsigned short* b0p = Bw + (size_t)col0 * 512 + ak0;
    const unsigned short* b1p = b0p + 16 * 512;

    f32x4 acc00 = f32x4{0.f,0.f,0.f,0.f}, acc01 = acc00, acc10 = acc00, acc11 = acc00;
#pragma unroll 4
    for (int k = 0; k < 512; k += 32) {
        bf8_t a0 = *(const bf8_t*)(a0p + k);
        bf8_t a1 = *(const bf8_t*)(a1p + k);
        bf8_t b0 = *(const bf8_t*)(b0p + k);
        bf8_t b1 = *(const bf8_t*)(b1p + k);
        acc00 = __builtin_amdgcn_mfma_f32_16x16x32_bf16(a0, b0, acc00, 0, 0, 0);
        acc01 = __builtin_amdgcn_mfma_f32_16x16x32_bf16(a0, b1, acc01, 0, 0, 0);
        acc10 = __builtin_amdgcn_mfma_f32_16x16x32_bf16(a1, b0, acc10, 0, 0, 0);
        acc11 = __builtin_amdgcn_mfma_f32_16x16x32_bf16(a1, b1, acc11, 0, 0, 0);
    }

    const float b1c0 = b1f[col0], b1c1 = b1f[col0 + 16];
    const float vc0 = vf[col0],  vc1 = vf[col0 + 16];
    float q = 0.f;
#pragma unroll
    for (int r = 0; r < 4; ++r) {
        q += tanhf(acc00[r] + b1c0) * vc0;
        q += tanhf(acc01[r] + b1c1) * vc1;
        q += tanhf(acc10[r] + b1c0) * vc0;
        q += tanhf(acc11[r] + b1c1) * vc1;
    }
#pragma unroll
    for (int m = 1; m < 64; m <<= 1) q += __shfl_xor(q, m, 64);
    __shared__ float red[4];
    if (lane == 0) red[wid] = q;
    __syncthreads();
    if (tid == 0) atomicAdd(&wsum[tm], red[0] + red[1] + red[2] + red[3]);
}

// ---------------------------------------------------------------------------
// score: ONE WAVE per (b,p); combines beta*z in-register (round-9 proven)
// ---------------------------------------------------------------------------
__device__ __forceinline__ void comb8(uint4 q0, uint4 q1, float b0, float b1,
                                      float* __restrict__ o)
{
    o[0] = b0 * bf2f(q0.x & 0xffffu) + b1 * bf2f(q1.x & 0xffffu);
    o[1] = b0 * hi16f(q0.x)          + b1 * hi16f(q1.x);
    o[2] = b0 * bf2f(q0.y & 0xffffu) + b1 * bf2f(q1.y & 0xffffu);
    o[3] = b0 * hi16f(q0.y)          + b1 * hi16f(q1.y);
    o[4] = b0 * bf2f(q0.z & 0xffffu) + b1 * bf2f(q1.z & 0xffffu);
    o[5] = b0 * hi16f(q0.z)          + b1 * hi16f(q1.z);
    o[6] = b0 * bf2f(q0.w & 0xffffu) + b1 * bf2f(q1.w & 0xffffu);
    o[7] = b0 * hi16f(q0.w)          + b1 * hi16f(q1.w);
}

__global__ __launch_bounds__(64) void score_kernel(
    const unsigned short* __restrict__ zb,
    const float* __restrict__ wsum,
    const int* __restrict__ uid, const int* __restrict__ pos,
    const int* __restrict__ neg, float* __restrict__ out)
{
    const int bp = blockIdx.x, b = bp >> 3;
    const int lane = threadIdx.x;
    const int c0 = lane * 8;

    const float wu0 = wsum[0] * (1.f / (float)NN), wu1 = wsum[1] * (1.f / (float)NN);
    const float mu = fmaxf(wu0, wu1);
    const float eu0 = __expf(wu0 - mu), eu1 = __expf(wu1 - mu);
    const float su = 1.f / (eu0 + eu1);
    const float bu0 = eu0 * su, bu1 = eu1 * su;
    const float wi0 = wsum[2] * (1.f / (float)NN), wi1 = wsum[3] * (1.f / (float)NN);
    const float mi = fmaxf(wi0, wi1);
    const float ei0 = __expf(wi0 - mi), ei1 = __expf(wi1 - mi);
    const float si = 1.f / (ei0 + ei1);
    const float bi0 = ei0 * si, bi1 = ei1 * si;

    const unsigned short* zu0 = zb;
    const unsigned short* zu1 = zb + (size_t)NN * 512;
    const unsigned short* zi0 = zb + (size_t)2 * NN * 512;
    const unsigned short* zi1 = zb + (size_t)3 * NN * 512;

    float* pos_logits = out;
    float* neg_logits = out + 8192;
    float* ue_n       = out + 73728;
    float* pe         = out + 33628160;
    float* ne         = out + 37822464;

    float u[8];
    {
        const size_t off = (size_t)uid[b] * 512 + c0;
        comb8(*(const uint4*)(zu0 + off), *(const uint4*)(zu1 + off), bu0, bu1, u);
    }

    // positive
    {
        const size_t off = (size_t)pos[bp] * 512 + c0;
        float pv[8];
        comb8(*(const uint4*)(zi0 + off), *(const uint4*)(zi1 + off), bi0, bi1, pv);
        float* pr = pe + (size_t)bp * 512 + c0;
        *(float4*)(pr)     = make_float4(pv[0], pv[1], pv[2], pv[3]);
        *(float4*)(pr + 4) = make_float4(pv[4], pv[5], pv[6], pv[7]);
        float d = u[0]*pv[0] + u[1]*pv[1] + u[2]*pv[2] + u[3]*pv[3]
                + u[4]*pv[4] + u[5]*pv[5] + u[6]*pv[6] + u[7]*pv[7];
#pragma unroll
        for (int off2 = 32; off2; off2 >>= 1) d += __shfl_down(d, off2, 64);
        if (lane == 0) pos_logits[bp] = d;
    }

    // negatives
    for (int k = 0; k < 8; ++k) {
        const size_t row = (size_t)bp * 8 + k;
        const size_t off = (size_t)neg[row] * 512 + c0;
        float nv[8];
        comb8(*(const uint4*)(zi0 + off), *(const uint4*)(zi1 + off), bi0, bi1, nv);
        float* nr = ne + row * 512 + c0;
        *(float4*)(nr)     = make_float4(nv[0], nv[1], nv[2], nv[3]);
        *(float4*)(nr + 4) = make_float4(nv[4], nv[5], nv[6], nv[7]);
        float* ur = ue_n + row * 512 + c0;
        *(float4*)(ur)     = make_float4(u[0], u[1], u[2], u[3]);
        *(float4*)(ur + 4) = make_float4(u[4], u[5], u[6], u[7]);
        float d = u[0]*nv[0] + u[1]*nv[1] + u[2]*nv[2] + u[3]*nv[3]
                + u[4]*nv[4] + u[5]*nv[5] + u[6]*nv[6] + u[7]*nv[7];
#pragma unroll
        for (int off2 = 32; off2; off2 >>= 1) d += __shfl_down(d, off2, 64);
        if (lane == 0) neg_logits[row] = d;
    }
}

// ---------------------------------------------------------------------------
extern "C" void kernel_launch(void* const* d_in, const int* in_sizes, int n_in,
                              void* d_out, int out_size, void* d_ws, size_t ws_size,
                              hipStream_t stream)
{
    const float* user_embs = (const float*)d_in[0];
    const float* item_embs = (const float*)d_in[1];
    const float* Wg_u = (const float*)d_in[2];
    const float* al_u = (const float*)d_in[3];
    const float* ar_u = (const float*)d_in[4];
    const float* bg_u = (const float*)d_in[5];
    const float* Ws_u = (const float*)d_in[6];
    const float* bs_u = (const float*)d_in[7];
    const float* vs_u = (const float*)d_in[8];
    const float* Wg_i = (const float*)d_in[9];
    const float* al_i = (const float*)d_in[10];
    const float* ar_i = (const float*)d_in[11];
    const float* bg_i = (const float*)d_in[12];
    const float* Ws_i = (const float*)d_in[13];
    const float* bs_i = (const float*)d_in[14];
    const float* vs_i = (const float*)d_in[15];
    const int* src_u = (const int*)d_in[16];
    const int* dst_u = (const int*)d_in[17];
    const int* src_i = (const int*)d_in[18];
    const int* dst_i = (const int*)d_in[19];
    const int* uid = (const int*)d_in[20];
    const int* pos = (const int*)d_in[21];
    const int* neg = (const int*)d_in[22];

    char* p = (char*)d_ws;
    auto carve = [&](size_t bytes) {
        char* r = p; p += (bytes + 255) & ~(size_t)255; return r;
    };
    unsigned short* fb  = (unsigned short*)carve((size_t)4 * NN * 512 * 2);  // 81.92 MB
    unsigned short* zb  = (unsigned short*)carve((size_t)4 * NN * 512 * 2);  // 81.92 MB
    unsigned short* hb  = (unsigned short*)carve((size_t)2 * NN * 64 * 2);
    unsigned short* Wt  = (unsigned short*)carve((size_t)4 * 512 * 64 * 2);
    unsigned short* W1t = (unsigned short*)carve((size_t)2 * 128 * 512 * 2);
    float* el   = (float*)carve((size_t)4 * NN * 8 * 4);
    float* er   = (float*)carve((size_t)4 * NN * 8 * 4);
    float* wsum = (float*)carve(64);
    int* count  = (int*)carve((size_t)4 * NN * 4);
    int* cursor = (int*)carve((size_t)4 * NN * 4);
    int* roff   = (int*)carve((size_t)4 * (NN + 1) * 4);
    int* csrc   = (int*)carve((size_t)4 * EE * 4);

    prep_kernel<<<(2 * NN * 64 + 255) / 256, 256, 0, stream>>>(
        user_embs, item_embs, Wg_u, Wg_i, Ws_u, Ws_i, hb, Wt, W1t,
        count, cursor, wsum);
    hist_kernel<<<dim3((EE + 255) / 256, 4), 256, 0, stream>>>(dst_u, dst_i, count);
    scan_kernel<<<4, 1024, 0, stream>>>(count, roff);
    scatter_fc_kernel<<<dim3(782 + NN / 16, 4), 256, 0, stream>>>(
        src_u, dst_u, src_i, dst_i, roff, cursor, csrc,
        hb, Wt, al_u, ar_u, al_i, ar_i, fb, el, er);
    agg_kernel<<<dim3(NN / 4, 4), 256, 0, stream>>>(
        fb, el, er, roff, csrc, bg_u, bg_i, zb);
    sem_kernel<<<dim3(NN / 32, 4), 256, 0, stream>>>(
        zb, W1t, bs_u, vs_u, bs_i, vs_i, wsum);
    score_kernel<<<1024 * 8, 64, 0, stream>>>(zb, wsum, uid, pos, neg, (float*)d_out);
}